// Round 3
// baseline (586.412 us; speedup 1.0000x reference)
//
#include <hip/hip_runtime.h>
#include <hip/hip_bf16.h>

namespace {

constexpr int S_LEN  = 2048;
constexpr int DH     = 128;
constexpr int NG     = 16;     // global tokens
constexpr int HALF_W = 256;    // WINDOW/2
constexpr int TQ     = 64;     // q rows per workgroup
constexpr int TK     = 32;     // keys per tile
constexpr int NT     = S_LEN / TK;  // 64
constexpr int BH     = 32;     // B*H

typedef __attribute__((ext_vector_type(8))) short bf16x8;
typedef __attribute__((ext_vector_type(4))) float f32x4;

// hi = truncation to bf16 (1 op); residual returned for the lo part.
__device__ __forceinline__ unsigned short bfhi(float x, float& rem) {
  unsigned b = __builtin_bit_cast(unsigned, x);
  unsigned short h = (unsigned short)(b >> 16);
  rem = x - __builtin_bit_cast(float, (unsigned)h << 16);
  return h;
}
// plain truncation (for the residual; error ~2^-16 relative overall)
__device__ __forceinline__ unsigned short bftr(float x) {
  return (unsigned short)(__builtin_bit_cast(unsigned, x) >> 16);
}
// round-half-up to bf16 (2 ops; error <= 2^-9 rel) — for V and P
__device__ __forceinline__ unsigned short bfrn(float x) {
  return (unsigned short)((__builtin_bit_cast(unsigned, x) + 0x8000u) >> 16);
}

__global__ __launch_bounds__(256, 3)
void gla_fwd(const float* __restrict__ Q, const float* __restrict__ K,
             const float* __restrict__ V, float* __restrict__ O)
{
  __shared__ unsigned short khi[TK * DH];       // 8 KB
  __shared__ unsigned short klo[TK * DH];       // 8 KB
  __shared__ unsigned short plds[4 * 16 * TK];  // 4 KB (1 KB per wave)

  const int tid  = threadIdx.x;
  const int w    = tid >> 6;
  const int l    = tid & 63;
  const int lo16 = l & 15;
  const int g    = l >> 4;

  // XCD-aware block swizzle (1024 % 8 == 0 -> bijective)
  const int nwg  = BH * (S_LEN / TQ);          // 1024
  const int cpx  = nwg >> 3;                   // 128
  const int bsw  = (blockIdx.x & 7) * cpx + (blockIdx.x >> 3);

  const int bh = bsw >> 5;            // 0..31
  const int i0 = (bsw & 31) * TQ;     // q row-tile base
  const int qb = i0 + w * 16;         // this wave's q base

  const size_t base = (size_t)bh * S_LEN * DH;
  const float* Qb = Q + base;
  const float* Kb = K + base;
  const float* Vb = V + base;
  float*       Ob = O + base;

  // ---- Q fragments: scaled, hi/lo split. A-frag: lane holds Q[qb+lo16][32c+8g+j]
  bf16x8 qhi[4], qlo[4];
  {
    const float scale = 0.08838834764831845f;  // 1/sqrt(128)
    const float* qp = Qb + (size_t)(qb + lo16) * DH + g * 8;
#pragma unroll
    for (int c = 0; c < 4; ++c) {
      float4 a = *(const float4*)(qp + c * 32);
      float4 b = *(const float4*)(qp + c * 32 + 4);
      float xs[8] = {a.x, a.y, a.z, a.w, b.x, b.y, b.z, b.w};
#pragma unroll
      for (int j = 0; j < 8; ++j) {
        float x = xs[j] * scale, r;
        qhi[c][j] = (short)bfhi(x, r);
        qlo[c][j] = (short)bftr(r);
      }
    }
  }

  const f32x4 zero4 = {0.f, 0.f, 0.f, 0.f};
  f32x4 accO[8];
#pragma unroll
  for (int dt = 0; dt < 8; ++dt) accO[dt] = zero4;
  float mrow[4] = {-1e30f, -1e30f, -1e30f, -1e30f};
  float lrow[4] = {0.f, 0.f, 0.f, 0.f};

  int t_lo = (i0 - HALF_W) >> 5; if (t_lo < 0) t_lo = 0;
  int t_hi = (i0 + TQ - 1 + HALF_W) >> 5;
  if (i0 == 0) t_hi = NT - 1;               // global rows see everything
  if (t_hi > NT - 1) t_hi = NT - 1;
  const int tstart = (t_lo > 1) ? t_lo : 1; // tile 0 handled explicitly

  // ---- T14 async-STAGE: K tile for iteration ti is loaded to regs during ti-1
  float4 kreg[4];
  auto load_ktile = [&](int kt) {
#pragma unroll
    for (int i = 0; i < 4; ++i) {
      const int e   = (i * 256 + tid) * 4;
      const int row = e >> 7;
      const int d   = e & 127;
      kreg[i] = *(const float4*)(Kb + (size_t)(kt + row) * DH + d);
    }
  };
  load_ktile(0);   // prologue: tile 0

  for (int ti = 0;; ++ti) {
    const int t = (ti == 0) ? 0 : (tstart + ti - 1);
    if (ti > 0 && t > t_hi) break;
    const int kt = t * TK;

    __syncthreads();   // all waves done reading previous LDS tile
    // ---- cvt + write staged regs -> LDS bf16 hi/lo, XOR-swizzled ----
#pragma unroll
    for (int i = 0; i < 4; ++i) {
      const int e   = (i * 256 + tid) * 4;
      const int row = e >> 7;
      const int d   = e & 127;
      float4 f = kreg[i];
      ushort4 hv, lv;
      float r;
      hv.x = bfhi(f.x, r); lv.x = bftr(r);
      hv.y = bfhi(f.y, r); lv.y = bftr(r);
      hv.z = bfhi(f.z, r); lv.z = bftr(r);
      hv.w = bfhi(f.w, r); lv.w = bftr(r);
      const int byte = (row * 256 + d * 2) ^ ((row & 7) << 4);
      *(ushort4*)((char*)khi + byte) = hv;
      *(ushort4*)((char*)klo + byte) = lv;
    }
    __syncthreads();   // tile t visible to all waves

    // ---- prefetch next K tile into regs (block-uniform; overlaps compute) ----
    const int tn = (ti == 0) ? tstart : t + 1;
    if (tn <= t_hi) load_ktile(tn * TK);

    // per-wave skip of fully-masked tiles (barriers stay uniform)
    const bool wave_active =
        ((kt + TK - 1 >= qb - HALF_W) && (kt <= qb + 15 + HALF_W)) ||
        (t == 0) || (qb < NG);
    if (!wave_active) continue;

    // ---- QK^T: scores[4g+r][n*16+lo16], hi/lo split (3 mfma / 32-d chunk) ----
    f32x4 sc[2];
    __builtin_amdgcn_s_setprio(1);
#pragma unroll
    for (int n = 0; n < 2; ++n) {
      f32x4 acc = zero4;
      const int row = n * 16 + lo16;        // key within tile
      const int swz = (row & 7) << 4;
      const int rb  = row * 256;
#pragma unroll
      for (int c = 0; c < 4; ++c) {
        int byte = (rb + c * 64 + g * 16) ^ swz;
        bf16x8 kh = *(bf16x8*)((char*)khi + byte);
        bf16x8 kl = *(bf16x8*)((char*)klo + byte);
        acc = __builtin_amdgcn_mfma_f32_16x16x32_bf16(qhi[c], kl, acc, 0, 0, 0);
        acc = __builtin_amdgcn_mfma_f32_16x16x32_bf16(qlo[c], kh, acc, 0, 0, 0);
        acc = __builtin_amdgcn_mfma_f32_16x16x32_bf16(qhi[c], kh, acc, 0, 0, 0);
      }
      sc[n] = acc;
    }
    __builtin_amdgcn_s_setprio(0);

    // ---- V fragments, direct from global (L1/L2-served; reused across blocks) ----
    // B-frag: lane holds V[kt+8g+j][16dt+lo16]
    bf16x8 vb[8];
    {
      const float* vp = Vb + (size_t)(kt + g * 8) * DH + lo16;
#pragma unroll
      for (int dt = 0; dt < 8; ++dt) {
        float tmp[8];
#pragma unroll
        for (int j = 0; j < 8; ++j) tmp[j] = vp[(size_t)j * DH + dt * 16];
#pragma unroll
        for (int j = 0; j < 8; ++j) vb[dt][j] = (short)bfrn(tmp[j]);
      }
    }

    // ---- mask (skip when tile fully inside every row's window) ----
    const bool full = (kt >= qb + 15 - HALF_W) && (kt + TK - 1 <= qb + HALF_W);
    if (!full) {
#pragma unroll
      for (int n = 0; n < 2; ++n) {
        const int j = kt + n * 16 + lo16;
#pragma unroll
        for (int r = 0; r < 4; ++r) {
          const int i = qb + g * 4 + r;
          const bool ok = ((unsigned)(j - i + HALF_W) <= 2u * HALF_W) ||
                          (j < NG) || (i < NG);
          if (!ok) sc[n][r] = -3.0e4f;
        }
      }
    }

    // ---- online softmax with defer-max (T13) ----
    f32x4 tmax;
#pragma unroll
    for (int r = 0; r < 4; ++r) tmax[r] = fmaxf(sc[0][r], sc[1][r]);
#pragma unroll
    for (int mo = 1; mo < 16; mo <<= 1) {
#pragma unroll
      for (int r = 0; r < 4; ++r)
        tmax[r] = fmaxf(tmax[r], __shfl_xor(tmax[r], mo, 64));
    }
    bool small = true;
#pragma unroll
    for (int r = 0; r < 4; ++r) small &= (tmax[r] <= mrow[r] + 8.0f);
    if (!__all(small)) {
      // full rescale path (rare after tile 0)
      float fr[4];
#pragma unroll
      for (int r = 0; r < 4; ++r) {
        float mnew = fmaxf(mrow[r], tmax[r]);
        fr[r]   = __expf(mrow[r] - mnew);
        mrow[r] = mnew;
        lrow[r] *= fr[r];
      }
#pragma unroll
      for (int dt = 0; dt < 8; ++dt) {
#pragma unroll
        for (int r = 0; r < 4; ++r) accO[dt][r] *= fr[r];
      }
    }
    float psum[4];
#pragma unroll
    for (int r = 0; r < 4; ++r) {
      float p0 = __expf(sc[0][r] - mrow[r]);   // bounded by e^8 under defer
      float p1 = __expf(sc[1][r] - mrow[r]);
      sc[0][r] = p0; sc[1][r] = p1;
      psum[r] = p0 + p1;
    }
#pragma unroll
    for (int mo = 1; mo < 16; mo <<= 1) {
#pragma unroll
      for (int r = 0; r < 4; ++r)
        psum[r] += __shfl_xor(psum[r], mo, 64);
    }
#pragma unroll
    for (int r = 0; r < 4; ++r) lrow[r] += psum[r];

    // ---- P: C-layout -> LDS (swizzled) -> A-fragment ----
    unsigned short* pw = plds + w * (16 * TK);
#pragma unroll
    for (int n = 0; n < 2; ++n) {
#pragma unroll
      for (int r = 0; r < 4; ++r) {
        const int m_ = g * 4 + r;
        const int byte = (m_ * 64 + (n * 16 + lo16) * 2) ^ ((m_ & 7) << 4);
        *(unsigned short*)((char*)pw + byte) = bfrn(sc[n][r]);
      }
    }
    bf16x8 pa;
    {
      const int byte = (lo16 * 64 + g * 16) ^ ((lo16 & 7) << 4);
      pa = *(bf16x8*)((char*)pw + byte);
    }

    // ---- P·V ----
    __builtin_amdgcn_s_setprio(1);
#pragma unroll
    for (int dt = 0; dt < 8; ++dt)
      accO[dt] = __builtin_amdgcn_mfma_f32_16x16x32_bf16(pa, vb[dt], accO[dt], 0, 0, 0);
    __builtin_amdgcn_s_setprio(0);
  }

  // ---- epilogue: normalize + store ----
  float inv[4];
#pragma unroll
  for (int r = 0; r < 4; ++r) inv[r] = 1.0f / lrow[r];
#pragma unroll
  for (int dt = 0; dt < 8; ++dt) {
#pragma unroll
    for (int r = 0; r < 4; ++r) {
      const int row = qb + g * 4 + r;
      Ob[(size_t)row * DH + dt * 16 + lo16] = accO[dt][r] * inv[r];
    }
  }
}

}  // namespace

extern "C" void kernel_launch(void* const* d_in, const int* in_sizes, int n_in,
                              void* d_out, int out_size, void* d_ws, size_t ws_size,
                              hipStream_t stream) {
  (void)in_sizes; (void)n_in; (void)out_size; (void)d_ws; (void)ws_size;
  const float* q = (const float*)d_in[0];
  const float* k = (const float*)d_in[1];
  const float* v = (const float*)d_in[2];
  float* o = (float*)d_out;
  dim3 grid(BH * (S_LEN / TQ));   // 1024 workgroups
  dim3 block(256);                // 4 waves
  gla_fwd<<<grid, block, 0, stream>>>(q, k, v, o);
}